// Round 1
// baseline (1063.149 us; speedup 1.0000x reference)
//
#include <hip/hip_runtime.h>
#include <stdint.h>

// ---------------- types ----------------
typedef __attribute__((ext_vector_type(8))) short short8;   // 8 x bf16 (4 VGPR) MFMA A/B frag
typedef __attribute__((ext_vector_type(4))) short short4v;  // 8B packed LDS write
typedef __attribute__((ext_vector_type(4))) float float4v;  // MFMA C/D frag

__device__ __forceinline__ short f2bf(float f) {
  uint32_t u = __builtin_bit_cast(uint32_t, f);
  u += 0x7FFFu + ((u >> 16) & 1u);   // round-to-nearest-even
  return (short)(u >> 16);
}

// async global->LDS, 16B per lane, wave-uniform LDS base
__device__ __forceinline__ void gl_lds16(const short* g, short* l) {
  __builtin_amdgcn_global_load_lds(
      (const __attribute__((address_space(1))) unsigned int*)g,
      (__attribute__((address_space(3))) unsigned int*)l, 16, 0, 0);
}

// ---------------- constants ----------------
// DIM=512, HEADS=8, D=64, N=64, B=2048 windows, MLON=64, PER_LAT=225
#define XPITCH 520   // 512 + 8: row stride 1040B = 260 dw == 4 mod 32 -> conflict-light b128
#define QPITCH 72    // 64 + 8:  row stride 144B = 36 dw == 4 mod 32

// =====================================================================
// Kernel 1: convert weights to bf16 in workspace
// =====================================================================
__global__ void prep_weights(const float* __restrict__ wq, const float* __restrict__ wp,
                             short* __restrict__ wq_b, short* __restrict__ wp_b) {
  int i = blockIdx.x * blockDim.x + threadIdx.x;
  int stride = gridDim.x * blockDim.x;
  for (int j = i; j < 786432 / 4; j += stride) {
    float4 v = ((const float4*)wq)[j];
    short4v t = {f2bf(v.x), f2bf(v.y), f2bf(v.z), f2bf(v.w)};
    ((short4v*)wq_b)[j] = t;
  }
  for (int j = i; j < 262144 / 4; j += stride) {
    float4 v = ((const float4*)wp)[j];
    short4v t = {f2bf(v.x), f2bf(v.y), f2bf(v.z), f2bf(v.w)};
    ((short4v*)wp_b)[j] = t;
  }
}

// =====================================================================
// Kernel 2: fused QKV-GEMM + window attention.  1 block = 1 window (64 tokens).
// 512 threads = 8 waves. Per round of 2 heads:
//   phase1 (MERGED): each wave owns exactly {one Qt strip, one Kt strip, one V
//     strip} (verified equal to the old s=w,w+8,w+16 assignment).  All three
//     consume the SAME 4 Xs fragments per K-iter, so one K-loop with 3 acc sets
//     reads Xs once: 4 ds_read_b128 per 12 MFMA instead of 12 per 12 (3x less
//     LDS traffic -- the measured bottleneck: 5.9e7 bank-conflict cycles).
//   phase2: wave -> (head, 16-row strip): S=Qs*Ks^T + analytic earth bias,
//     row softmax via shfl_xor within 16-lane groups, P->Qs rows (wave-LOCAL
//     round trip -- no barrier needed), O=P*Vt, bf16 store to attn workspace.
// =====================================================================
__global__ __launch_bounds__(512, 2)
void qkv_attn(const float* __restrict__ x, const short* __restrict__ wq,
              const float* __restrict__ bqkv, const float* __restrict__ btab,
              short* __restrict__ attn) {
  __shared__ short Xs[64 * XPITCH];        // 66,560 B
  __shared__ short Qs[2][64 * QPITCH];     // 18,432 B
  __shared__ short Ks[2][64 * QPITCH];     // 18,432 B
  __shared__ short Vt[2][64 * QPITCH];     // 18,432 B   total 121,856 B

  const int b    = blockIdx.x;
  const int tid  = threadIdx.x;
  const int lane = tid & 63;
  const int w    = tid >> 6;       // wave 0..7
  const int l16  = lane & 15;
  const int quad = lane >> 4;      // 0..3
  const int lat  = b >> 6;         // MLON = 64

  // ---- stage X window into LDS as bf16 ----
  const float* xw = x + (size_t)b * (64 * 512);
  for (int c = tid; c < 64 * 128; c += 512) {   // float4 chunks
    int n = c >> 7, kc = c & 127;
    float4 v = *(const float4*)(xw + n * 512 + kc * 4);
    short4v t = {f2bf(v.x), f2bf(v.y), f2bf(v.z), f2bf(v.w)};
    *(short4v*)&Xs[n * XPITCH + kc * 4] = t;
  }
  __syncthreads();

  // static per-wave strip assignment (== old s=w,w+8,w+16 coverage):
  //   g=0 (waves 0-3): Qt(h0,st), Kt(h1,st), V(h0,st)
  //   g=1 (waves 4-7): Qt(h1,st), Kt(h0,st), V(h1,st)
  const int g  = w >> 2;
  const int st = w & 3;

  for (int h0 = 0; h0 < 8; h0 += 2) {
    // ---------------- phase 1: QKV GEMMs (strip-merged) ----------------
    {
      const int hq = h0 + g;         // Qt + V head
      const int hk = h0 + 1 - g;     // Kt head
      const short* Aq = wq + (size_t)((hq * 64 + st * 16 + l16) * 512) + quad * 8;
      const short* Ak = wq + (size_t)(((512) + hk * 64 + st * 16 + l16) * 512) + quad * 8;
      const short* Av = wq + (size_t)(((1024) + hq * 64 + st * 16 + l16) * 512) + quad * 8;
      const short* xb0 = &Xs[l16 * XPITCH + quad * 8];
      const short* xb1 = xb0 + 16 * XPITCH;
      const short* xb2 = xb0 + 32 * XPITCH;
      const short* xb3 = xb0 + 48 * XPITCH;

      float4v aQ[4] = {}, aK[4] = {}, aV[4] = {};
#pragma unroll 4
      for (int kk = 0; kk < 512; kk += 32) {
        short8 wqf = *(const short8*)(Aq + kk);
        short8 wkf = *(const short8*)(Ak + kk);
        short8 wvf = *(const short8*)(Av + kk);
        short8 x0 = *(const short8*)(xb0 + kk);
        short8 x1 = *(const short8*)(xb1 + kk);
        short8 x2 = *(const short8*)(xb2 + kk);
        short8 x3 = *(const short8*)(xb3 + kk);
        aQ[0] = __builtin_amdgcn_mfma_f32_16x16x32_bf16(wqf, x0, aQ[0], 0, 0, 0);
        aQ[1] = __builtin_amdgcn_mfma_f32_16x16x32_bf16(wqf, x1, aQ[1], 0, 0, 0);
        aQ[2] = __builtin_amdgcn_mfma_f32_16x16x32_bf16(wqf, x2, aQ[2], 0, 0, 0);
        aQ[3] = __builtin_amdgcn_mfma_f32_16x16x32_bf16(wqf, x3, aQ[3], 0, 0, 0);
        aK[0] = __builtin_amdgcn_mfma_f32_16x16x32_bf16(wkf, x0, aK[0], 0, 0, 0);
        aK[1] = __builtin_amdgcn_mfma_f32_16x16x32_bf16(wkf, x1, aK[1], 0, 0, 0);
        aK[2] = __builtin_amdgcn_mfma_f32_16x16x32_bf16(wkf, x2, aK[2], 0, 0, 0);
        aK[3] = __builtin_amdgcn_mfma_f32_16x16x32_bf16(wkf, x3, aK[3], 0, 0, 0);
        aV[0] = __builtin_amdgcn_mfma_f32_16x16x32_bf16(x0, wvf, aV[0], 0, 0, 0);
        aV[1] = __builtin_amdgcn_mfma_f32_16x16x32_bf16(x1, wvf, aV[1], 0, 0, 0);
        aV[2] = __builtin_amdgcn_mfma_f32_16x16x32_bf16(x2, wvf, aV[2], 0, 0, 0);
        aV[3] = __builtin_amdgcn_mfma_f32_16x16x32_bf16(x3, wvf, aV[3], 0, 0, 0);
      }

      // ---- epilogues (identical math to unmerged version) ----
      float bq[4], bk[4];
#pragma unroll
      for (int i = 0; i < 4; ++i) {
        bq[i] = bqkv[hq * 64 + st * 16 + quad * 4 + i];
        bk[i] = bqkv[512 + hk * 64 + st * 16 + quad * 4 + i];
      }
      short* dq = &Qs[g][0];
      short* dk = &Ks[1 - g][0];
#pragma unroll
      for (int t = 0; t < 4; ++t) {
        int n = t * 16 + l16;
        short4v pq, pk;
#pragma unroll
        for (int i = 0; i < 4; ++i) {
          pq[i] = f2bf((aQ[t][i] + bq[i]) * 0.125f);   // fold q-scale (exact pow2)
          pk[i] = f2bf(aK[t][i] + bk[i]);
        }
        *(short4v*)&dq[n * QPITCH + st * 16 + quad * 4] = pq;  // [n][d] packed
        *(short4v*)&dk[n * QPITCH + st * 16 + quad * 4] = pk;
      }
      float bv = bqkv[1024 + hq * 64 + st * 16 + l16];
#pragma unroll
      for (int t = 0; t < 4; ++t) {
        // lane holds V[m = t*16 + quad*4 + i][d = st*16 + l16]
        short4v pv;
#pragma unroll
        for (int i = 0; i < 4; ++i) pv[i] = f2bf(aV[t][i] + bv);
        *(short4v*)&Vt[g][(st * 16 + l16) * QPITCH + t * 16 + quad * 4] = pv;  // [d][m]
      }
    }
    __syncthreads();

    // ---------------- phase 2: attention ----------------
    {
      const int hsel = w >> 2;
      const int h    = h0 + hsel;
      const int n0   = (w & 3) * 16;

      // S = Q * K^T  (K-dim = d = 64)
      float4v s4[4] = {};
#pragma unroll
      for (int kd = 0; kd < 64; kd += 32) {
        short8 a = *(const short8*)&Qs[hsel][(n0 + l16) * QPITCH + kd + quad * 8];
#pragma unroll
        for (int t = 0; t < 4; ++t) {
          short8 bf = *(const short8*)&Ks[hsel][(t * 16 + l16) * QPITCH + kd + quad * 8];
          s4[t] = __builtin_amdgcn_mfma_f32_16x16x32_bf16(a, bf, s4[t], 0, 0, 0);
        }
      }
      // analytic earth bias (skips rel_idx input entirely)
#pragma unroll
      for (int t = 0; t < 4; ++t) {
        int m = t * 16 + l16;
#pragma unroll
        for (int i = 0; i < 4; ++i) {
          int n = n0 + quad * 4 + i;
          int idx = ((n >> 3) - (m >> 3) + 7) * 15 + ((n & 7) - (m & 7) + 7) + lat * 225;
          s4[t][i] += btab[idx * 8 + h];
        }
      }
      // row softmax: row n held at fixed reg i across 16 lanes of the quad
      float p[4][4];
#pragma unroll
      for (int i = 0; i < 4; ++i) {
        float mx = fmaxf(fmaxf(s4[0][i], s4[1][i]), fmaxf(s4[2][i], s4[3][i]));
        mx = fmaxf(mx, __shfl_xor(mx, 1));
        mx = fmaxf(mx, __shfl_xor(mx, 2));
        mx = fmaxf(mx, __shfl_xor(mx, 4));
        mx = fmaxf(mx, __shfl_xor(mx, 8));
        float e0 = __expf(s4[0][i] - mx), e1 = __expf(s4[1][i] - mx);
        float e2 = __expf(s4[2][i] - mx), e3 = __expf(s4[3][i] - mx);
        float sm = e0 + e1 + e2 + e3;
        sm += __shfl_xor(sm, 1);
        sm += __shfl_xor(sm, 2);
        sm += __shfl_xor(sm, 4);
        sm += __shfl_xor(sm, 8);
        float inv = 1.0f / sm;
        p[0][i] = e0 * inv; p[1][i] = e1 * inv; p[2][i] = e2 * inv; p[3][i] = e3 * inv;
      }
      // P -> LDS (overwrite own Q rows; wave-local round trip -- no barrier:
      // each wave writes and reads ONLY rows [n0, n0+16) of Qs[hsel])
#pragma unroll
      for (int t = 0; t < 4; ++t)
#pragma unroll
        for (int i = 0; i < 4; ++i)
          Qs[hsel][(n0 + quad * 4 + i) * QPITCH + t * 16 + l16] = f2bf(p[t][i]);

      // O = P * V  (K-dim = m = 64)
      float4v o4[4] = {};
#pragma unroll
      for (int km = 0; km < 64; km += 32) {
        short8 a = *(const short8*)&Qs[hsel][(n0 + l16) * QPITCH + km + quad * 8];
#pragma unroll
        for (int t = 0; t < 4; ++t) {
          short8 bf = *(const short8*)&Vt[hsel][(t * 16 + l16) * QPITCH + km + quad * 8];
          o4[t] = __builtin_amdgcn_mfma_f32_16x16x32_bf16(a, bf, o4[t], 0, 0, 0);
        }
      }
      // store attn[b][n][h*64 + d] as bf16
      short* ob = attn + (size_t)b * (64 * 512);
#pragma unroll
      for (int t = 0; t < 4; ++t)
#pragma unroll
        for (int i = 0; i < 4; ++i)
          ob[(n0 + quad * 4 + i) * 512 + h * 64 + t * 16 + l16] = f2bf(o4[t][i]);
    }
    __syncthreads();   // protect Qs/Ks/Vt before next head round
  }
}

// =====================================================================
// Kernel 3: out = attn(131072x512 bf16) @ w_proj^T + b_proj   (fp32 out)
// m97-style: 128x128 tile, BK=64, global_load_lds width-16 staging,
// 2 barriers per K-step, 4 waves each owning a 64x64 quadrant.
// 1D grid 4096 with bijective XCD swizzle (4096 % 8 == 0) so the 4 blocks
// sharing an A(m)-panel co-reside on one XCD's L2.
// =====================================================================
__global__ __launch_bounds__(256, 2)
void proj_gemm(const short* __restrict__ attn, const short* __restrict__ wp,
               const float* __restrict__ bproj, float* __restrict__ out) {
  __shared__ short As[128 * 64];   // 16 KB, rows of attn (m)
  __shared__ short Bs[128 * 64];   // 16 KB, rows of wp  (n)

  // XCD-bijective remap (nwg=4096, r=0): wg = xcd*512 + orig/8
  const int orig = blockIdx.x;
  const int wg   = (orig & 7) * 512 + (orig >> 3);
  const int n0   = (wg & 3) * 128;   // n fastest: 4 n-blocks per A-panel
  const int m0   = (wg >> 2) * 128;

  const int tid  = threadIdx.x;
  const int lane = tid & 63;
  const int w    = tid >> 6;
  const int l16  = lane & 15;
  const int quad = lane >> 4;
  const int wm   = w >> 1, wn = w & 1;

  // staging geometry: 16 chunks of 1KB (8 rows) per matrix; wave w owns 4
  const int srow = lane >> 3;          // row within chunk (0..7)
  const int scol = (lane & 7) * 8;     // shorts (16B units)

  float4v acc[4][4] = {};

  for (int kk = 0; kk < 512; kk += 64) {
#pragma unroll
    for (int j = 0; j < 4; ++j) {
      int chunk = w * 4 + j;                 // 0..15
      int row = chunk * 8 + srow;
      gl_lds16(attn + (size_t)(m0 + row) * 512 + kk + scol, &As[chunk * 512]);
      gl_lds16(wp + (size_t)(n0 + row) * 512 + kk + scol, &Bs[chunk * 512]);
    }
    __syncthreads();   // compiler emits vmcnt(0) drain before barrier
#pragma unroll
    for (int ks = 0; ks < 64; ks += 32) {
      short8 a[4], bf[4];
#pragma unroll
      for (int ti = 0; ti < 4; ++ti)
        a[ti] = *(const short8*)&As[(wm * 64 + ti * 16 + l16) * 64 + ks + quad * 8];
#pragma unroll
      for (int tj = 0; tj < 4; ++tj)
        bf[tj] = *(const short8*)&Bs[(wn * 64 + tj * 16 + l16) * 64 + ks + quad * 8];
#pragma unroll
      for (int ti = 0; ti < 4; ++ti)
#pragma unroll
        for (int tj = 0; tj < 4; ++tj)
          acc[ti][tj] = __builtin_amdgcn_mfma_f32_16x16x32_bf16(a[ti], bf[tj], acc[ti][tj], 0, 0, 0);
    }
    __syncthreads();
  }

  float bj[4];
#pragma unroll
  for (int tj = 0; tj < 4; ++tj) bj[tj] = bproj[n0 + wn * 64 + tj * 16 + l16];
#pragma unroll
  for (int ti = 0; ti < 4; ++ti)
#pragma unroll
    for (int i = 0; i < 4; ++i) {
      size_t rowoff = (size_t)(m0 + wm * 64 + ti * 16 + quad * 4 + i) * 512;
#pragma unroll
      for (int tj = 0; tj < 4; ++tj)
        out[rowoff + n0 + wn * 64 + tj * 16 + l16] = acc[ti][tj][i] + bj[tj];
    }
}

// =====================================================================
extern "C" void kernel_launch(void* const* d_in, const int* in_sizes, int n_in,
                              void* d_out, int out_size, void* d_ws, size_t ws_size,
                              hipStream_t stream) {
  const float* x     = (const float*)d_in[0];   // (2048, 64, 512)
  const float* wqkv  = (const float*)d_in[1];   // (1536, 512)
  const float* bqkv  = (const float*)d_in[2];   // (1536,)
  const float* wproj = (const float*)d_in[3];   // (512, 512)
  const float* bproj = (const float*)d_in[4];   // (512,)
  const float* btab  = (const float*)d_in[5];   // (7200, 8)
  // d_in[6] = rel_idx -- recomputed analytically in-kernel, not read.
  float* out = (float*)d_out;

  short* wq_b = (short*)d_ws;            // 786,432 bf16
  short* wp_b = wq_b + 786432;           // 262,144 bf16
  short* attn = wp_b + 262144;           // 67,108,864 bf16 (~128 MB); ws use ~130 MB

  prep_weights<<<256, 256, 0, stream>>>(wqkv, wproj, wq_b, wp_b);
  qkv_attn<<<2048, 512, 0, stream>>>(x, wq_b, bqkv, btab, attn);
  proj_gemm<<<4096, 256, 0, stream>>>(attn, wp_b, bproj, out);
}